// Round 3
// baseline (170.991 us; speedup 1.0000x reference)
//
#include <hip/hip_runtime.h>
#include <hip/hip_bf16.h>

typedef __bf16 bf16x8 __attribute__((ext_vector_type(8)));
typedef __bf16 bf16x4 __attribute__((ext_vector_type(4)));
typedef float  f32x4  __attribute__((ext_vector_type(4)));

#define NSEG   39
#define NCAT   26
#define NCTS   13
#define VOCAB  100000
#define DIM    64
#define HID    512
#define KTOT   2496   // 39*64
#define BROWS  64
#define RD     4      // gather prefetch depth

__global__ void w1_to_bf16(const float* __restrict__ w1, ushort* __restrict__ w1b, int n4) {
    int i = blockIdx.x * blockDim.x + threadIdx.x;
    if (i >= n4) return;
    f32x4 v = ((const f32x4*)w1)[i];
    ushort4 o;
    o.x = __builtin_bit_cast(unsigned short, (__bf16)v[0]);
    o.y = __builtin_bit_cast(unsigned short, (__bf16)v[1]);
    o.z = __builtin_bit_cast(unsigned short, (__bf16)v[2]);
    o.w = __builtin_bit_cast(unsigned short, (__bf16)v[3]);
    ((ushort4*)w1b)[i] = o;
}

template<bool W1BF>
__global__ __launch_bounds__(1024, 4)
void fused_net(const float* __restrict__ x,      // B x 39
               const float* __restrict__ emb,    // 26 x V x 64
               const float* __restrict__ ctsW,   // 13 x 64
               const float* __restrict__ ctsB,   // 13 x 64
               const void*  __restrict__ W1p,    // 512 x 2496 (bf16 or f32)
               const float* __restrict__ b1,     // 512
               const float* __restrict__ W2,     // 512
               const float* __restrict__ b2,     // 1
               float* __restrict__ out)          // B
{
    const int tid  = threadIdx.x;
    const int lane = tid & 63;
    const int wave = tid >> 6;
    const int mg   = wave & 1;   // rows mg*32 .. +31
    const int ng   = wave >> 1;  // cols ng*64 .. +63
    const int m0   = blockIdx.x * BROWS;

    __shared__ float xs[BROWS * NSEG];                    // 9984 B
    __shared__ float ctsw_s[NCTS * DIM];                  // 3328 B
    __shared__ float ctsb_s[NCTS * DIM];                  // 3328 B
    __shared__ __align__(16) ushort Abuf[2][BROWS * DIM]; // 2 x 8 KB bf16, swizzled
    __shared__ float hsum[BROWS];

    for (int e = tid; e < BROWS * NSEG; e += 1024)
        xs[e] = x[(size_t)m0 * NSEG + e];
    for (int e = tid; e < NCTS * DIM; e += 1024) {
        ctsw_s[e] = ctsW[e];
        ctsb_s[e] = ctsB[e];
    }
    if (tid < BROWS) hsum[tid] = 0.f;
    __syncthreads();

    // staging: thread -> (row r, 16B f32 chunk s16). LDS position: bf16 slot pp, half hh.
    // content chunk cch = swizzled so that read (R,C) finds chunk C at slot C^(R&7).
    const int r    = tid >> 4;
    const int s16  = tid & 15;
    const int pp   = s16 >> 1;
    const int hh   = s16 & 1;
    const int cch  = ((pp ^ (r & 7)) << 1) | hh;        // f32x4 chunk index 0..15
    const int wbyte = r * 128 + pp * 16 + hh * 8;       // LDS byte offset in buf

    unsigned bbase[4];
#pragma unroll
    for (int ni = 0; ni < 4; ++ni)
        bbase[ni] = (unsigned)(ng * 64 + ni * 16 + (lane & 15)) * KTOT + ((lane >> 4) << 3);

    const ushort* W1b = (const ushort*)W1p;
    const float*  W1f = (const float*)W1p;

    f32x4 g[RD];

    auto issueCat = [&](int t, int j) {
        int idx = (int)xs[r * NSEG + t];
        const float* ptr = emb + ((size_t)t * VOCAB + (size_t)idx) * DIM + cch * 4;
        g[j] = __builtin_nontemporal_load((const f32x4*)ptr);
    };

    auto writeA = [&](int t, int j, int buf) {
        float vv[4];
        if (t < NCAT) {
#pragma unroll
            for (int k = 0; k < 4; ++k) vv[k] = g[j][k];
            if (t >= 1) {
#pragma unroll
                for (int k = 0; k < 4; ++k) vv[k] = fmaxf(vv[k], 0.f);
            }
        } else {
            int jj = t - NCAT;
            float sx = xs[r * NSEG + t];
            f32x4 w = *(const f32x4*)&ctsw_s[jj * DIM + cch * 4];
            f32x4 q = *(const f32x4*)&ctsb_s[jj * DIM + cch * 4];
#pragma unroll
            for (int k = 0; k < 4; ++k) vv[k] = fmaxf(fmaf(sx, w[k], q[k]), 0.f);
        }
        bf16x4 o;
#pragma unroll
        for (int k = 0; k < 4; ++k) o[k] = (__bf16)vv[k];
        *(bf16x4*)((char*)Abuf[buf] + wbyte) = o;
    };

    f32x4 acc[2][4];
#pragma unroll
    for (int mi = 0; mi < 2; ++mi)
#pragma unroll
        for (int ni = 0; ni < 4; ++ni)
            acc[mi][ni] = (f32x4){0.f, 0.f, 0.f, 0.f};

    // prologue: fill gather ring, stage tile 0, first barrier
#pragma unroll
    for (int j = 0; j < RD; ++j) issueCat(j, j);
    writeA(0, 0, 0);
    asm volatile("s_waitcnt lgkmcnt(0)" ::: "memory");
    __builtin_amdgcn_s_barrier();
    __builtin_amdgcn_sched_barrier(0);

    for (int tt = 0; tt < 40; tt += RD) {
#pragma unroll
        for (int j = 0; j < RD; ++j) {
            const int t = tt + j;
            if (t < NSEG) {
                const int buf = j & 1;  // == t&1 since tt%4==0

                // B fragments for this step (single-buffered, issued first)
                bf16x8 bfr[2][4];
#pragma unroll
                for (int ks = 0; ks < 2; ++ks)
#pragma unroll
                    for (int ni = 0; ni < 4; ++ni) {
                        unsigned off = bbase[ni] + t * 64 + ks * 32;
                        if constexpr (W1BF) {
                            bfr[ks][ni] = *(const bf16x8*)(W1b + off);
                        } else {
                            f32x4 u0 = *(const f32x4*)(W1f + off);
                            f32x4 u1 = *(const f32x4*)(W1f + off + 4);
                            bf16x8 tmp;
#pragma unroll
                            for (int k = 0; k < 4; ++k) {
                                tmp[k]     = (__bf16)u0[k];
                                tmp[4 + k] = (__bf16)u1[k];
                            }
                            bfr[ks][ni] = tmp;
                        }
                    }

                // next gather (lands ~4 steps from now)
                if (t + RD < NCAT) issueCat(t + RD, j);

                // A fragments from LDS (swizzled)
                bf16x8 afr[2][2];
#pragma unroll
                for (int ks = 0; ks < 2; ++ks)
#pragma unroll
                    for (int mi = 0; mi < 2; ++mi) {
                        int R = mg * 32 + mi * 16 + (lane & 15);
                        int C = ks * 4 + (lane >> 4);
                        afr[ks][mi] = *(const bf16x8*)((const char*)Abuf[buf]
                                        + R * 128 + ((C ^ (R & 7)) << 4));
                    }

#pragma unroll
                for (int ks = 0; ks < 2; ++ks)
#pragma unroll
                    for (int ni = 0; ni < 4; ++ni)
#pragma unroll
                        for (int mi = 0; mi < 2; ++mi)
                            acc[mi][ni] = __builtin_amdgcn_mfma_f32_16x16x32_bf16(
                                afr[ks][mi], bfr[ks][ni], acc[mi][ni], 0, 0, 0);

                // stage next tile into the other buffer
                if (t + 1 < NSEG) writeA(t + 1, (j + 1) & 3, buf ^ 1);

                asm volatile("s_waitcnt lgkmcnt(0)" ::: "memory");
                __builtin_amdgcn_s_barrier();
                __builtin_amdgcn_sched_barrier(0);
            }
        }
    }

    // epilogue: p = relu(acc + b1) . W2 partial per lane, reduce over 16-lane n-group
    float pv[2][4];
#pragma unroll
    for (int mi = 0; mi < 2; ++mi)
#pragma unroll
        for (int rg = 0; rg < 4; ++rg) pv[mi][rg] = 0.f;

#pragma unroll
    for (int ni = 0; ni < 4; ++ni) {
        int n = ng * 64 + ni * 16 + (lane & 15);
        float b1v = b1[n];
        float w2v = W2[n];
#pragma unroll
        for (int mi = 0; mi < 2; ++mi)
#pragma unroll
            for (int rg = 0; rg < 4; ++rg) {
                float h = fmaxf(acc[mi][ni][rg] + b1v, 0.f);
                pv[mi][rg] = fmaf(h, w2v, pv[mi][rg]);
            }
    }

#pragma unroll
    for (int m = 1; m < 16; m <<= 1)
#pragma unroll
        for (int mi = 0; mi < 2; ++mi)
#pragma unroll
            for (int rg = 0; rg < 4; ++rg)
                pv[mi][rg] += __shfl_xor(pv[mi][rg], m, 64);

    if ((lane & 15) == 0) {
        int rq = lane >> 4;
#pragma unroll
        for (int mi = 0; mi < 2; ++mi)
#pragma unroll
            for (int rg = 0; rg < 4; ++rg)
                atomicAdd(&hsum[mg * 32 + mi * 16 + rq * 4 + rg], pv[mi][rg]);
    }
    __syncthreads();

    if (tid < BROWS) out[m0 + tid] = expf(hsum[tid] + b2[0]);
}

extern "C" void kernel_launch(void* const* d_in, const int* in_sizes, int n_in,
                              void* d_out, int out_size, void* d_ws, size_t ws_size,
                              hipStream_t stream) {
    const float* x    = (const float*)d_in[0];
    const float* emb  = (const float*)d_in[1];
    const float* ctsW = (const float*)d_in[2];
    const float* ctsB = (const float*)d_in[3];
    const float* W1   = (const float*)d_in[4];
    const float* b1   = (const float*)d_in[5];
    const float* W2   = (const float*)d_in[6];
    const float* b2   = (const float*)d_in[7];
    float* out = (float*)d_out;

    const int Bn = in_sizes[0] / NSEG;           // 16384
    const int nblk = Bn / BROWS;                 // 256
    const size_t w1b_bytes = (size_t)HID * KTOT * sizeof(unsigned short);

    if (ws_size >= w1b_bytes) {
        ushort* W1b = (ushort*)d_ws;
        int n4 = HID * KTOT / 4;
        w1_to_bf16<<<(n4 + 255) / 256, 256, 0, stream>>>(W1, W1b, n4);
        fused_net<true><<<nblk, 1024, 0, stream>>>(x, emb, ctsW, ctsB, (const void*)W1b,
                                                   b1, W2, b2, out);
    } else {
        fused_net<false><<<nblk, 1024, 0, stream>>>(x, emb, ctsW, ctsB, (const void*)W1,
                                                    b1, W2, b2, out);
    }
}

// Round 4
// 110.018 us; speedup vs baseline: 1.5542x; 1.5542x over previous
//
#include <hip/hip_runtime.h>
#include <hip/hip_bf16.h>

typedef __bf16 bf16x8 __attribute__((ext_vector_type(8)));
typedef float  f32x4  __attribute__((ext_vector_type(4)));

#define NSEG   39
#define NCAT   26
#define NCTS   13
#define VOCAB  100000
#define DIM    64
#define HID    512
#define KTOT   2496   // 39*64
#define MT     128    // rows per block
#define NT     256    // h-cols per block (N-half)

__global__ void w1_to_bf16(const float* __restrict__ w1, ushort* __restrict__ w1b, int n4) {
    int i = blockIdx.x * blockDim.x + threadIdx.x;
    if (i >= n4) return;
    f32x4 v = ((const f32x4*)w1)[i];
    ushort4 o;
    o.x = __builtin_bit_cast(unsigned short, (__bf16)v[0]);
    o.y = __builtin_bit_cast(unsigned short, (__bf16)v[1]);
    o.z = __builtin_bit_cast(unsigned short, (__bf16)v[2]);
    o.w = __builtin_bit_cast(unsigned short, (__bf16)v[3]);
    ((ushort4*)w1b)[i] = o;
}

__global__ void zero_out_k(float* __restrict__ out) {
    out[blockIdx.x * 256 + threadIdx.x] = 0.f;
}

__global__ void exp_out_k(float* __restrict__ out, const float* __restrict__ b2) {
    int i = blockIdx.x * 256 + threadIdx.x;
    out[i] = expf(out[i] + b2[0]);
}

template<bool W1BF>
__global__ __launch_bounds__(512, 2)
void fused_net(const float* __restrict__ x,      // B x 39
               const float* __restrict__ emb,    // 26 x V x 64
               const float* __restrict__ ctsW,   // 13 x 64
               const float* __restrict__ ctsB,   // 13 x 64
               const void*  __restrict__ W1p,    // 512 x 2496 (bf16 or f32)
               const float* __restrict__ b1,     // 512
               const float* __restrict__ W2,     // 512
               float* __restrict__ out)          // B (partial accumulate)
{
    const int tid  = threadIdx.x;
    const int lane = tid & 63;
    const int wave = tid >> 6;
    const int mg   = wave & 1;   // row half: mg*64
    const int ng   = wave >> 1;  // col group: ng*64 (within NT=256)

    // sibling blocks (same mtile, nhalf 0/1) differ by 8 -> same XCD (round-robin %8)
    const int bid   = blockIdx.x;
    const int mtile = (bid >> 4) * 8 + (bid & 7);
    const int nhalf = (bid >> 3) & 1;
    const int m0    = mtile * MT;
    const int n0    = nhalf * NT;

    __shared__ float xs[MT * NSEG];                      // 19968 B
    __shared__ float ctsw_s[NCTS * DIM];                 // 3328 B
    __shared__ float ctsb_s[NCTS * DIM];                 // 3328 B
    __shared__ __align__(16) ushort Abuf[2][MT * DIM];   // 2 x 16 KB bf16, swizzled
    __shared__ float hsum[MT];                           // 512 B

    for (int e = tid; e < MT * NSEG; e += 512)
        xs[e] = x[(size_t)m0 * NSEG + e];
    for (int e = tid; e < NCTS * DIM; e += 512) {
        ctsw_s[e] = ctsW[e];
        ctsb_s[e] = ctsB[e];
    }
    if (tid < MT) hsum[tid] = 0.f;
    __syncthreads();

    // staging geometry: thread -> row r (4 thr/row), 16-elem group q4.
    // content chunks c = 2*q4, 2*q4+1 (8 bf16 elems each); physical slot = c ^ (r&7).
    const int r    = tid >> 2;
    const int q4   = tid & 3;
    const int kswz = r & 7;

    unsigned bbase[4];
#pragma unroll
    for (int ni = 0; ni < 4; ++ni)
        bbase[ni] = (unsigned)(n0 + ng * 64 + ni * 16 + (lane & 15)) * KTOT + ((lane >> 4) << 3);

    const ushort* W1b = (const ushort*)W1p;
    const float*  W1f = (const float*)W1p;

    // gather ring: 3 segments deep, 16 floats (64 B) per thread per segment
    f32x4 g[3][4];

    auto issueG = [&](int t, int slot) {
        int idx = (int)xs[r * NSEG + t];
        const float* p = emb + ((size_t)t * VOCAB + (size_t)idx) * DIM + q4 * 16;
        g[slot][0] = *(const f32x4*)(p);
        g[slot][1] = *(const f32x4*)(p + 4);
        g[slot][2] = *(const f32x4*)(p + 8);
        g[slot][3] = *(const f32x4*)(p + 12);
    };

    auto writeA = [&](int seg, int slot, int buf, bool norelu) {
        float v[16];
        if (seg < NCAT) {
#pragma unroll
            for (int i = 0; i < 4; ++i)
#pragma unroll
                for (int w = 0; w < 4; ++w) v[i * 4 + w] = g[slot][i][w];
            if (!norelu) {
#pragma unroll
                for (int k = 0; k < 16; ++k) v[k] = fmaxf(v[k], 0.f);
            }
        } else {
            int jj = seg - NCAT;
            float sx = xs[r * NSEG + seg];
#pragma unroll
            for (int i = 0; i < 4; ++i) {
                f32x4 w  = *(const f32x4*)&ctsw_s[jj * DIM + q4 * 16 + i * 4];
                f32x4 bb = *(const f32x4*)&ctsb_s[jj * DIM + q4 * 16 + i * 4];
#pragma unroll
                for (int k = 0; k < 4; ++k)
                    v[i * 4 + k] = fmaxf(fmaf(sx, w[k], bb[k]), 0.f);
            }
        }
        bf16x8 o0, o1;
#pragma unroll
        for (int k = 0; k < 8; ++k) { o0[k] = (__bf16)v[k]; o1[k] = (__bf16)v[8 + k]; }
        const int p0 = (2 * q4) ^ kswz;
        const int p1 = (2 * q4 + 1) ^ kswz;
        *(bf16x8*)&Abuf[buf][r * DIM + p0 * 8] = o0;
        *(bf16x8*)&Abuf[buf][r * DIM + p1 * 8] = o1;
    };

    bf16x8 bfr[2][2][4];  // [set][ks][ni]
    auto loadB = [&](int t, int set) {
#pragma unroll
        for (int ks = 0; ks < 2; ++ks)
#pragma unroll
            for (int ni = 0; ni < 4; ++ni) {
                unsigned off = bbase[ni] + t * 64 + ks * 32;
                if constexpr (W1BF) {
                    bfr[set][ks][ni] = *(const bf16x8*)(W1b + off);
                } else {
                    f32x4 u0 = *(const f32x4*)(W1f + off);
                    f32x4 u1 = *(const f32x4*)(W1f + off + 4);
                    bf16x8 tmp;
#pragma unroll
                    for (int k = 0; k < 4; ++k) {
                        tmp[k]     = (__bf16)u0[k];
                        tmp[4 + k] = (__bf16)u1[k];
                    }
                    bfr[set][ks][ni] = tmp;
                }
            }
    };

    f32x4 acc[4][4];
#pragma unroll
    for (int mi = 0; mi < 4; ++mi)
#pragma unroll
        for (int ni = 0; ni < 4; ++ni)
            acc[mi][ni] = (f32x4){0.f, 0.f, 0.f, 0.f};

    // prologue: fill gather ring (segs 0..2), first B set, stage seg 0
    issueG(0, 0);
    issueG(1, 1);
    issueG(2, 2);
    loadB(0, 0);
    writeA(0, 0, 0, /*norelu=*/true);
    asm volatile("s_waitcnt lgkmcnt(0)" ::: "memory");
    __builtin_amdgcn_s_barrier();
    __builtin_amdgcn_sched_barrier(0);

    for (int tt = 0; tt < 42; tt += 6) {
#pragma unroll
        for (int j = 0; j < 6; ++j) {
            const int t = tt + j;
            if (t < NSEG) {
                if (t + 1 < NSEG) loadB(t + 1, (j + 1) & 1);
                if (t + 3 < NCAT) issueG(t + 3, (j + 3) % 3);

#pragma unroll
                for (int ks = 0; ks < 2; ++ks) {
                    bf16x8 afr[4];
#pragma unroll
                    for (int mi = 0; mi < 4; ++mi) {
                        int R = mg * 64 + mi * 16 + (lane & 15);
                        int C = ks * 4 + (lane >> 4);
                        afr[mi] = *(const bf16x8*)&Abuf[j & 1][R * DIM + ((C ^ (R & 7)) << 3)];
                    }
                    __builtin_amdgcn_s_setprio(1);
#pragma unroll
                    for (int ni = 0; ni < 4; ++ni)
#pragma unroll
                        for (int mi = 0; mi < 4; ++mi)
                            acc[mi][ni] = __builtin_amdgcn_mfma_f32_16x16x32_bf16(
                                afr[mi], bfr[j & 1][ks][ni], acc[mi][ni], 0, 0, 0);
                    __builtin_amdgcn_s_setprio(0);
                }

                if (t + 1 < NSEG) writeA(t + 1, (j + 1) % 3, (j + 1) & 1, false);

                asm volatile("s_waitcnt lgkmcnt(0)" ::: "memory");
                __builtin_amdgcn_s_barrier();
                __builtin_amdgcn_sched_barrier(0);
            }
        }
    }

    // epilogue: pv = sum_n relu(acc + b1) * W2 over this block's 256 cols
    float pv[4][4];
#pragma unroll
    for (int mi = 0; mi < 4; ++mi)
#pragma unroll
        for (int rg = 0; rg < 4; ++rg) pv[mi][rg] = 0.f;

#pragma unroll
    for (int ni = 0; ni < 4; ++ni) {
        int n = n0 + ng * 64 + ni * 16 + (lane & 15);
        float b1v = b1[n];
        float w2v = W2[n];
#pragma unroll
        for (int mi = 0; mi < 4; ++mi)
#pragma unroll
            for (int rg = 0; rg < 4; ++rg) {
                float h = fmaxf(acc[mi][ni][rg] + b1v, 0.f);
                pv[mi][rg] = fmaf(h, w2v, pv[mi][rg]);
            }
    }

#pragma unroll
    for (int m = 1; m < 16; m <<= 1)
#pragma unroll
        for (int mi = 0; mi < 4; ++mi)
#pragma unroll
            for (int rg = 0; rg < 4; ++rg)
                pv[mi][rg] += __shfl_xor(pv[mi][rg], m, 64);

    if ((lane & 15) == 0) {
        int rq = lane >> 4;
#pragma unroll
        for (int mi = 0; mi < 4; ++mi)
#pragma unroll
            for (int rg = 0; rg < 4; ++rg)
                atomicAdd(&hsum[mg * 64 + mi * 16 + rq * 4 + rg], pv[mi][rg]);
    }
    __syncthreads();

    // add this block's partial into global out (sibling adds the other N-half)
    if (tid < MT) atomicAdd(&out[m0 + tid], hsum[tid]);
}

extern "C" void kernel_launch(void* const* d_in, const int* in_sizes, int n_in,
                              void* d_out, int out_size, void* d_ws, size_t ws_size,
                              hipStream_t stream) {
    const float* x    = (const float*)d_in[0];
    const float* emb  = (const float*)d_in[1];
    const float* ctsW = (const float*)d_in[2];
    const float* ctsB = (const float*)d_in[3];
    const float* W1   = (const float*)d_in[4];
    const float* b1   = (const float*)d_in[5];
    const float* W2   = (const float*)d_in[6];
    const float* b2   = (const float*)d_in[7];
    float* out = (float*)d_out;

    const int Bn   = in_sizes[0] / NSEG;         // 16384
    const int nblk = (Bn / MT) * 2;              // 256
    const size_t w1b_bytes = (size_t)HID * KTOT * sizeof(unsigned short);

    zero_out_k<<<Bn / 256, 256, 0, stream>>>(out);

    if (ws_size >= w1b_bytes) {
        ushort* W1b = (ushort*)d_ws;
        int n4 = HID * KTOT / 4;
        w1_to_bf16<<<(n4 + 255) / 256, 256, 0, stream>>>(W1, W1b, n4);
        fused_net<true><<<nblk, 512, 0, stream>>>(x, emb, ctsW, ctsB, (const void*)W1b,
                                                  b1, W2, out);
    } else {
        fused_net<false><<<nblk, 512, 0, stream>>>(x, emb, ctsW, ctsB, (const void*)W1,
                                                   b1, W2, out);
    }

    exp_out_k<<<Bn / 256, 256, 0, stream>>>(out, b2);
}